// Round 2
// baseline (159.940 us; speedup 1.0000x reference)
//
#include <hip/hip_runtime.h>
#include <hip/hip_bf16.h>

#define BATCH 2
#define DEPTH 64
#define HH 128
#define WW 128
#define SLICES (BATCH*DEPTH)
#define SLICE_ELEMS (HH*WW)
#define NBLK (SLICES*HH)

// ---------------- init: zero the per-batch thresholds ----------------
__global__ __launch_bounds__(64) void init_kernel(float* thresh) {
    if (threadIdx.x < BATCH) thresh[threadIdx.x] = 0.0f;
}

// ---------------- column pass: vertical 1D distances ----------------
// g_dst[i][j] = min |i-i'| over i' with threshed==0 (255 = none in column)
// g_inv[i][j] = min |i-i'| over i' with threshed==1 (255 = none in column)
__global__ __launch_bounds__(128) void colpass_kernel(const float* __restrict__ y_pred,
        unsigned char* __restrict__ g_dst, unsigned char* __restrict__ g_inv,
        int* __restrict__ present)
{
    __shared__ unsigned char m[HH][WW];
    __shared__ unsigned char gd[HH][WW];
    __shared__ unsigned char gi[HH][WW];
    __shared__ int anyfg;
    int s = blockIdx.x;
    int t = threadIdx.x;
    if (t == 0) anyfg = 0;
    __syncthreads();
    const float* base = y_pred + (size_t)s * SLICE_ELEMS;
    int local_any = 0;
    for (int r = 0; r < HH; ++r) {
        float v = base[r*WW + t];
        unsigned char fg = (v > 0.7f) ? 1 : 0;
        m[r][t] = fg;
        local_any |= fg;
    }
    if (local_any) anyfg = 1;
    __syncthreads();
    // thread t scans column t (its own column only -> no barrier needed below)
    int dd = 255, di = 255;
    for (int i = 0; i < HH; ++i) {
        int fg = m[i][t];
        dd = fg ? ((dd < 255) ? dd + 1 : 255) : 0;
        di = fg ? 0 : ((di < 255) ? di + 1 : 255);
        gd[i][t] = (unsigned char)dd;
        gi[i][t] = (unsigned char)di;
    }
    dd = 255; di = 255;
    for (int i = HH-1; i >= 0; --i) {
        int fg = m[i][t];
        dd = fg ? ((dd < 255) ? dd + 1 : 255) : 0;
        di = fg ? 0 : ((di < 255) ? di + 1 : 255);
        if (dd < (int)gd[i][t]) gd[i][t] = (unsigned char)dd;
        if (di < (int)gi[i][t]) gi[i][t] = (unsigned char)di;
    }
    // coalesced write-out (thread t reads its own column's values)
    unsigned char* od = g_dst + (size_t)s*SLICE_ELEMS;
    unsigned char* oi = g_inv + (size_t)s*SLICE_ELEMS;
    for (int r = 0; r < HH; ++r) {
        od[r*WW + t] = gd[r][t];
        oi[r*WW + t] = gi[r][t];
    }
    if (t == 0) present[s] = anyfg;
}

// ---------------- per-batch first/last present slice ----------------
__global__ __launch_bounds__(64) void range_kernel(const int* __restrict__ present,
                                                   int* __restrict__ firstlast)
{
    int b = threadIdx.x;
    if (b < BATCH) {
        int f = 0;                       // argmax(all false) == 0
        for (int d = DEPTH-1; d >= 0; --d) if (present[b*DEPTH+d]) f = d;
        int l = DEPTH-1;                 // D-1-argmax(all false) == D-1
        for (int d = 0; d < DEPTH; ++d)  if (present[b*DEPTH+d]) l = d;
        firstlast[b] = f;
        firstlast[BATCH + b] = l;
    }
}

// ---------------- thresh = max over dst slice at last[b] ----------------
__global__ __launch_bounds__(128) void thresh_kernel(const unsigned char* __restrict__ g_dst,
        const int* __restrict__ firstlast, float* __restrict__ thresh)
{
    int b = blockIdx.x / HH;
    int i = blockIdx.x % HH;
    int j = threadIdx.x;
    int last = firstlast[BATCH + b];
    int s = b*DEPTH + last;
    __shared__ float g2[WW];
    int v = g_dst[(size_t)s*SLICE_ELEMS + i*WW + j];
    g2[j] = (v >= 255) ? 1e20f : (float)(v*v);
    __syncthreads();
    float best = 3e38f;
    #pragma unroll 8
    for (int jp = 0; jp < WW; ++jp) {
        float df = (float)(j - jp);
        best = fminf(best, fmaf(df, df, g2[jp]));
    }
    float dval = sqrtf(best);
    for (int off = 32; off > 0; off >>= 1)
        dval = fmaxf(dval, __shfl_down(dval, off));
    __shared__ float wmax[2];
    if ((threadIdx.x & 63) == 0) wmax[threadIdx.x >> 6] = dval;
    __syncthreads();
    if (threadIdx.x == 0) {
        float mx = fmaxf(wmax[0], wmax[1]);
        atomicMax((int*)&thresh[b], __float_as_int(mx));  // vals >= 0 -> int order ok
    }
}

// ---------------- main: row min-plus pass + all partial sums ----------------
__global__ __launch_bounds__(128) void main_kernel(const float* __restrict__ y_pred,
        const float* __restrict__ y_true,
        const unsigned char* __restrict__ g_dst, const unsigned char* __restrict__ g_inv,
        const int* __restrict__ firstlast, const float* __restrict__ thresh,
        float* __restrict__ partials)
{
    int blk = blockIdx.x;
    int s = blk / HH;        // slice index (b*DEPTH + d)
    int i = blk % HH;        // row
    int j = threadIdx.x;     // column
    int b = s / DEPTH;
    int d = s % DEPTH;
    size_t rowoff = (size_t)s*SLICE_ELEMS + (size_t)i*WW;
    __shared__ float g2d[WW], g2i[WW];
    {
        int v = g_dst[rowoff + j];
        g2d[j] = (v >= 255) ? 1e20f : (float)(v*v);
        int u = g_inv[rowoff + j];
        g2i[j] = (u >= 255) ? 1e20f : (float)(u*u);
    }
    __syncthreads();
    float bd = 3e38f, bi = 3e38f;
    #pragma unroll 8
    for (int jp = 0; jp < WW; ++jp) {
        float df = (float)(j - jp);
        bd = fminf(bd, fmaf(df, df, g2d[jp]));
        bi = fminf(bi, fmaf(df, df, g2i[jp]));
    }
    float combined = sqrtf(bd) + sqrtf(bi);
    int first = firstlast[b], last = firstlast[BATCH + b];
    float c = (d >= first && d <= last) ? combined : 0.0f;
    c = fminf(c, thresh[b]);
    float yp = y_pred[rowoff + j];
    float yt = y_true[rowoff + j];
    float msk = (yt > 0.0f) ? 1.0f : 0.0f;
    float v0 = yp * yt;   // intersection
    float v1 = yp;        // sum y_pred
    float v2 = yt;        // sum y_true
    float v3 = msk * c;   // sum selected combined
    float v4 = msk;       // mask count
    for (int off = 32; off > 0; off >>= 1) {
        v0 += __shfl_down(v0, off);
        v1 += __shfl_down(v1, off);
        v2 += __shfl_down(v2, off);
        v3 += __shfl_down(v3, off);
        v4 += __shfl_down(v4, off);
    }
    __shared__ float wsum[2][5];
    int wv = threadIdx.x >> 6;
    if ((threadIdx.x & 63) == 0) {
        wsum[wv][0]=v0; wsum[wv][1]=v1; wsum[wv][2]=v2; wsum[wv][3]=v3; wsum[wv][4]=v4;
    }
    __syncthreads();
    if (threadIdx.x == 0) {
        partials[0*NBLK + blk] = wsum[0][0]+wsum[1][0];
        partials[1*NBLK + blk] = wsum[0][1]+wsum[1][1];
        partials[2*NBLK + blk] = wsum[0][2]+wsum[1][2];
        partials[3*NBLK + blk] = wsum[0][3]+wsum[1][3];
        partials[4*NBLK + blk] = wsum[0][4]+wsum[1][4];
    }
}

// ---------------- final: reduce partials, emit scalar loss ----------------
__global__ __launch_bounds__(256) void final_kernel(const float* __restrict__ partials,
                                                    float* __restrict__ out)
{
    double l0=0, l1=0, l2=0, l3=0, l4=0;
    for (int idx = threadIdx.x; idx < NBLK; idx += 256) {
        l0 += (double)partials[0*NBLK + idx];
        l1 += (double)partials[1*NBLK + idx];
        l2 += (double)partials[2*NBLK + idx];
        l3 += (double)partials[3*NBLK + idx];
        l4 += (double)partials[4*NBLK + idx];
    }
    for (int off = 32; off > 0; off >>= 1) {
        l0 += __shfl_down(l0, off);
        l1 += __shfl_down(l1, off);
        l2 += __shfl_down(l2, off);
        l3 += __shfl_down(l3, off);
        l4 += __shfl_down(l4, off);
    }
    __shared__ double ds[4][5];
    int wv = threadIdx.x >> 6;
    if ((threadIdx.x & 63) == 0) { ds[wv][0]=l0; ds[wv][1]=l1; ds[wv][2]=l2; ds[wv][3]=l3; ds[wv][4]=l4; }
    __syncthreads();
    if (threadIdx.x == 0) {
        double inter=0, spred=0, strue=0, sel=0, cnt=0;
        for (int w = 0; w < 4; ++w) {
            inter += ds[w][0]; spred += ds[w][1]; strue += ds[w][2];
            sel   += ds[w][3]; cnt   += ds[w][4];
        }
        double dice = 2.0 * inter / (spred + strue + 1e-6);
        double mean_sel = sel / cnt;
        double loss = (1.0 - dice) + 3.0 * fabs(1.0 - mean_sel);
        out[0] = (float)loss;
    }
}

extern "C" void kernel_launch(void* const* d_in, const int* in_sizes, int n_in,
                              void* d_out, int out_size, void* d_ws, size_t ws_size,
                              hipStream_t stream) {
    const float* y_pred = (const float*)d_in[0];
    const float* y_true = (const float*)d_in[1];
    float* out = (float*)d_out;
    char* ws = (char*)d_ws;

    float* thresh     = (float*)ws;                    // 2 floats
    int*   firstlast  = (int*)(ws + 64);               // 4 ints (first[2], last[2])
    int*   present    = (int*)(ws + 128);              // 128 ints
    float* partials   = (float*)(ws + 1024);           // 5 * 16384 floats = 320 KB
    unsigned char* g_dst = (unsigned char*)(ws + (512<<10));          // 2 MB
    unsigned char* g_inv = g_dst + (size_t)SLICES*SLICE_ELEMS;        // 2 MB

    init_kernel<<<1, 64, 0, stream>>>(thresh);
    colpass_kernel<<<SLICES, 128, 0, stream>>>(y_pred, g_dst, g_inv, present);
    range_kernel<<<1, 64, 0, stream>>>(present, firstlast);
    thresh_kernel<<<BATCH*HH, 128, 0, stream>>>(g_dst, firstlast, thresh);
    main_kernel<<<NBLK, 128, 0, stream>>>(y_pred, y_true, g_dst, g_inv, firstlast, thresh, partials);
    final_kernel<<<1, 256, 0, stream>>>(partials, out);
}

// Round 3
// 122.070 us; speedup vs baseline: 1.3102x; 1.3102x over previous
//
#include <hip/hip_runtime.h>
#include <hip/hip_bf16.h>

#define BATCH 2
#define DEPTH 64
#define HH 128
#define WW 128
#define SLICES (BATCH*DEPTH)
#define SLICE_ELEMS (HH*WW)
#define NBLK (SLICES*HH)

// ---------------- column pass: vertical 1D distances ----------------
// g_dst[i][j] = min |i-i'| over i' with threshed==0 (255 = none in column)
// g_inv[i][j] = min |i-i'| over i' with threshed==1 (255 = none in column)
__global__ __launch_bounds__(128) void colpass_kernel(const float* __restrict__ y_pred,
        unsigned char* __restrict__ g_dst, unsigned char* __restrict__ g_inv,
        int* __restrict__ present)
{
    __shared__ unsigned char m[HH][WW];
    __shared__ unsigned char gd[HH][WW];
    __shared__ unsigned char gi[HH][WW];
    __shared__ int anyfg;
    int s = blockIdx.x;
    int t = threadIdx.x;
    if (t == 0) anyfg = 0;
    __syncthreads();
    const float* base = y_pred + (size_t)s * SLICE_ELEMS;
    int local_any = 0;
    for (int r = 0; r < HH; ++r) {
        float v = base[r*WW + t];
        unsigned char fg = (v > 0.7f) ? 1 : 0;
        m[r][t] = fg;
        local_any |= fg;
    }
    if (local_any) anyfg = 1;
    __syncthreads();
    // thread t scans column t (its own column only -> no barrier needed below)
    int dd = 255, di = 255;
    for (int i = 0; i < HH; ++i) {
        int fg = m[i][t];
        dd = fg ? ((dd < 255) ? dd + 1 : 255) : 0;
        di = fg ? 0 : ((di < 255) ? di + 1 : 255);
        gd[i][t] = (unsigned char)dd;
        gi[i][t] = (unsigned char)di;
    }
    dd = 255; di = 255;
    for (int i = HH-1; i >= 0; --i) {
        int fg = m[i][t];
        dd = fg ? ((dd < 255) ? dd + 1 : 255) : 0;
        di = fg ? 0 : ((di < 255) ? di + 1 : 255);
        if (dd < (int)gd[i][t]) gd[i][t] = (unsigned char)dd;
        if (di < (int)gi[i][t]) gi[i][t] = (unsigned char)di;
    }
    // coalesced write-out (thread t reads its own column's values)
    unsigned char* od = g_dst + (size_t)s*SLICE_ELEMS;
    unsigned char* oi = g_inv + (size_t)s*SLICE_ELEMS;
    for (int r = 0; r < HH; ++r) {
        od[r*WW + t] = gd[r][t];
        oi[r*WW + t] = gi[r][t];
    }
    if (t == 0) present[s] = anyfg;
}

// ---------------- per-batch first/last present slice + zero thresh ----------------
__global__ __launch_bounds__(64) void range_kernel(const int* __restrict__ present,
                                                   int* __restrict__ firstlast,
                                                   float* __restrict__ thresh)
{
    int b = threadIdx.x;
    if (b < BATCH) {
        int f = 0;                       // argmax(all false) == 0
        for (int d = DEPTH-1; d >= 0; --d) if (present[b*DEPTH+d]) f = d;
        int l = DEPTH-1;                 // D-1-argmax(all false) == D-1
        for (int d = 0; d < DEPTH; ++d)  if (present[b*DEPTH+d]) l = d;
        firstlast[b] = f;
        firstlast[BATCH + b] = l;
        thresh[b] = 0.0f;
    }
}

// ---------------- thresh = max over dst slice at last[b] ----------------
__global__ __launch_bounds__(128) void thresh_kernel(const unsigned char* __restrict__ g_dst,
        const int* __restrict__ firstlast, float* __restrict__ thresh)
{
    int b = blockIdx.x / HH;
    int i = blockIdx.x % HH;
    int j = threadIdx.x;
    int last = firstlast[BATCH + b];
    int s = b*DEPTH + last;
    __shared__ float g2[WW];
    int v = g_dst[(size_t)s*SLICE_ELEMS + i*WW + j];
    g2[j] = (v >= 255) ? 1e20f : (float)(v*v);
    __syncthreads();
    // outward early-exit scan: cand(jp) = (j-jp)^2 + g2[jp] >= r^2, so once
    // r^2 >= best no farther column can improve -> exact.
    float bd = g2[j];
    for (int r = 1; r < WW; ++r) {
        float r2 = (float)(r*r);
        if (__all(r2 >= bd)) break;
        int jl = j - r, jr = j + r;
        float gl = g2[jl & (WW-1)]; gl = (jl >= 0) ? gl : 3e38f;
        float gr = g2[jr & (WW-1)]; gr = (jr < WW) ? gr : 3e38f;
        bd = fminf(bd, r2 + fminf(gl, gr));
    }
    float dval = sqrtf(bd);
    for (int off = 32; off > 0; off >>= 1)
        dval = fmaxf(dval, __shfl_down(dval, off));
    __shared__ float wmax[2];
    if ((threadIdx.x & 63) == 0) wmax[threadIdx.x >> 6] = dval;
    __syncthreads();
    if (threadIdx.x == 0) {
        float mx = fmaxf(wmax[0], wmax[1]);
        atomicMax((int*)&thresh[b], __float_as_int(mx));  // vals >= 0 -> int order ok
    }
}

// ---------------- main: row min-plus pass + all partial sums ----------------
__global__ __launch_bounds__(128) void main_kernel(const float* __restrict__ y_pred,
        const float* __restrict__ y_true,
        const unsigned char* __restrict__ g_dst, const unsigned char* __restrict__ g_inv,
        const int* __restrict__ firstlast, const float* __restrict__ thresh,
        float* __restrict__ partials)
{
    int blk = blockIdx.x;
    int s = blk / HH;        // slice index (b*DEPTH + d)
    int i = blk % HH;        // row
    int j = threadIdx.x;     // column
    int b = s / DEPTH;
    int d = s % DEPTH;
    size_t rowoff = (size_t)s*SLICE_ELEMS + (size_t)i*WW;
    // issue global loads early; consumed after the scan
    float yp = y_pred[rowoff + j];
    float yt = y_true[rowoff + j];
    __shared__ float g2d[WW], g2i[WW];
    {
        int v = g_dst[rowoff + j];
        g2d[j] = (v >= 255) ? 1e20f : (float)(v*v);
        int u = g_inv[rowoff + j];
        g2i[j] = (u >= 255) ? 1e20f : (float)(u*u);
    }
    __syncthreads();
    // outward early-exit scan over both maps simultaneously (exact; see thresh_kernel)
    float bd = g2d[j], bi = g2i[j];
    for (int r = 1; r < WW; ++r) {
        float r2 = (float)(r*r);
        if (__all((r2 >= bd) && (r2 >= bi))) break;
        int jl = j - r, jr = j + r;
        int jlc = jl & (WW-1), jrc = jr & (WW-1);
        float gld = g2d[jlc], gli = g2i[jlc];
        float grd = g2d[jrc], gri = g2i[jrc];
        gld = (jl >= 0) ? gld : 3e38f;  gli = (jl >= 0) ? gli : 3e38f;
        grd = (jr < WW) ? grd : 3e38f;  gri = (jr < WW) ? gri : 3e38f;
        bd = fminf(bd, r2 + fminf(gld, grd));
        bi = fminf(bi, r2 + fminf(gli, gri));
    }
    float combined = sqrtf(bd) + sqrtf(bi);
    int first = firstlast[b], last = firstlast[BATCH + b];
    float c = (d >= first && d <= last) ? combined : 0.0f;
    c = fminf(c, thresh[b]);
    float msk = (yt > 0.0f) ? 1.0f : 0.0f;
    float v0 = yp * yt;   // intersection
    float v1 = yp;        // sum y_pred
    float v2 = yt;        // sum y_true
    float v3 = msk * c;   // sum selected combined
    float v4 = msk;       // mask count
    for (int off = 32; off > 0; off >>= 1) {
        v0 += __shfl_down(v0, off);
        v1 += __shfl_down(v1, off);
        v2 += __shfl_down(v2, off);
        v3 += __shfl_down(v3, off);
        v4 += __shfl_down(v4, off);
    }
    __shared__ float wsum[2][5];
    int wv = threadIdx.x >> 6;
    if ((threadIdx.x & 63) == 0) {
        wsum[wv][0]=v0; wsum[wv][1]=v1; wsum[wv][2]=v2; wsum[wv][3]=v3; wsum[wv][4]=v4;
    }
    __syncthreads();
    if (threadIdx.x == 0) {
        partials[0*NBLK + blk] = wsum[0][0]+wsum[1][0];
        partials[1*NBLK + blk] = wsum[0][1]+wsum[1][1];
        partials[2*NBLK + blk] = wsum[0][2]+wsum[1][2];
        partials[3*NBLK + blk] = wsum[0][3]+wsum[1][3];
        partials[4*NBLK + blk] = wsum[0][4]+wsum[1][4];
    }
}

// ---------------- final: reduce partials, emit scalar loss ----------------
__global__ __launch_bounds__(1024) void final_kernel(const float* __restrict__ partials,
                                                     float* __restrict__ out)
{
    double l0=0, l1=0, l2=0, l3=0, l4=0;
    for (int idx = threadIdx.x; idx < NBLK; idx += 1024) {
        l0 += (double)partials[0*NBLK + idx];
        l1 += (double)partials[1*NBLK + idx];
        l2 += (double)partials[2*NBLK + idx];
        l3 += (double)partials[3*NBLK + idx];
        l4 += (double)partials[4*NBLK + idx];
    }
    for (int off = 32; off > 0; off >>= 1) {
        l0 += __shfl_down(l0, off);
        l1 += __shfl_down(l1, off);
        l2 += __shfl_down(l2, off);
        l3 += __shfl_down(l3, off);
        l4 += __shfl_down(l4, off);
    }
    __shared__ double ds[16][5];
    int wv = threadIdx.x >> 6;
    if ((threadIdx.x & 63) == 0) { ds[wv][0]=l0; ds[wv][1]=l1; ds[wv][2]=l2; ds[wv][3]=l3; ds[wv][4]=l4; }
    __syncthreads();
    if (threadIdx.x == 0) {
        double inter=0, spred=0, strue=0, sel=0, cnt=0;
        for (int w = 0; w < 16; ++w) {
            inter += ds[w][0]; spred += ds[w][1]; strue += ds[w][2];
            sel   += ds[w][3]; cnt   += ds[w][4];
        }
        double dice = 2.0 * inter / (spred + strue + 1e-6);
        double mean_sel = sel / cnt;
        double loss = (1.0 - dice) + 3.0 * fabs(1.0 - mean_sel);
        out[0] = (float)loss;
    }
}

extern "C" void kernel_launch(void* const* d_in, const int* in_sizes, int n_in,
                              void* d_out, int out_size, void* d_ws, size_t ws_size,
                              hipStream_t stream) {
    const float* y_pred = (const float*)d_in[0];
    const float* y_true = (const float*)d_in[1];
    float* out = (float*)d_out;
    char* ws = (char*)d_ws;

    float* thresh     = (float*)ws;                    // 2 floats
    int*   firstlast  = (int*)(ws + 64);               // 4 ints (first[2], last[2])
    int*   present    = (int*)(ws + 128);              // 128 ints
    float* partials   = (float*)(ws + 1024);           // 5 * 16384 floats = 320 KB
    unsigned char* g_dst = (unsigned char*)(ws + (512<<10));          // 2 MB
    unsigned char* g_inv = g_dst + (size_t)SLICES*SLICE_ELEMS;        // 2 MB

    colpass_kernel<<<SLICES, 128, 0, stream>>>(y_pred, g_dst, g_inv, present);
    range_kernel<<<1, 64, 0, stream>>>(present, firstlast, thresh);
    thresh_kernel<<<BATCH*HH, 128, 0, stream>>>(g_dst, firstlast, thresh);
    main_kernel<<<NBLK, 128, 0, stream>>>(y_pred, y_true, g_dst, g_inv, firstlast, thresh, partials);
    final_kernel<<<1, 1024, 0, stream>>>(partials, out);
}

// Round 4
// 106.497 us; speedup vs baseline: 1.5018x; 1.1462x over previous
//
#include <hip/hip_runtime.h>
#include <hip/hip_bf16.h>

#define BATCH 2
#define DEPTH 64
#define HH 128
#define WW 128
#define SLICES (BATCH*DEPTH)
#define SLICE_ELEMS (HH*WW)
#define NELEM (SLICES*SLICE_ELEMS)
#define NV4 (NELEM/4)
#define RBLK 1024

// ---------------- K1: fused column EDT + row min-plus, per half-slice ----------------
// combined(p) = distance from p to nearest opposite-class pixel (== dst+inv, since
// the same-class term is exactly 0). Column pass kept in registers as bitmasks;
// LDS holds packed (g_inv^2<<16)|g_dst^2 per cell (0xFFFF = none in column).
__global__ __launch_bounds__(256) void edt_kernel(const float* __restrict__ y_pred,
        float* __restrict__ combined, float* __restrict__ maxdst_blocks)
{
    __shared__ unsigned int tmp[HH][WW];   // 64 KB
    __shared__ float wred[4];
    int blk = blockIdx.x;
    int s  = blk >> 1;        // slice = b*DEPTH + d
    int hb = blk & 1;         // which 64-row half this block owns
    int t  = threadIdx.x;
    const float* base = y_pred + (size_t)s * SLICE_ELEMS;

    if (t < WW) {
        // build column-t bitmask (bit i = threshed pixel (i,t))
        unsigned mm[4];
        #pragma unroll
        for (int g = 0; g < 4; ++g) {
            unsigned acc = 0u;
            #pragma unroll
            for (int ii = 0; ii < 32; ++ii) {
                int r = g*32 + ii;
                acc |= (base[r*WW + t] > 0.7f ? 1u : 0u) << ii;
            }
            mm[g] = acc;
        }
        // forward scan: dd = dist to nearest 0 above, di = dist to nearest 1 above
        int dd = 300, di = 300;
        #pragma unroll
        for (int g = 0; g < 4; ++g) {
            unsigned mg = mm[g];
            #pragma unroll
            for (int ii = 0; ii < 32; ++ii) {
                int i = g*32 + ii;
                int fg = (mg >> ii) & 1;
                dd = fg ? dd + 1 : 0;
                di = fg ? 0 : di + 1;
                tmp[i][t] = ((unsigned)di << 16) | (unsigned)dd;
            }
        }
        // backward scan + min + square + sentinel, written packed in place
        dd = 300; di = 300;
        #pragma unroll
        for (int g = 3; g >= 0; --g) {
            unsigned mg = mm[g];
            #pragma unroll
            for (int ii = 31; ii >= 0; --ii) {
                int i = g*32 + ii;
                int fg = (mg >> ii) & 1;
                dd = fg ? dd + 1 : 0;
                di = fg ? 0 : di + 1;
                unsigned p = tmp[i][t];
                int fd = min((int)(p & 0xFFFFu), dd);
                int fi = min((int)(p >> 16), di);
                unsigned sd = (fd >= 128) ? 0xFFFFu : (unsigned)(fd*fd);
                unsigned si = (fi >= 128) ? 0xFFFFu : (unsigned)(fi*fi);
                tmp[i][t] = (si << 16) | sd;
            }
        }
    }
    __syncthreads();

    // row phase: 2 rows per iteration (256 threads = 2 rows x 128 cols)
    int j  = t & (WW-1);
    int ri = t >> 7;          // 0 or 1
    float dmax = 0.0f;
    float* cbase = combined + (size_t)s * SLICE_ELEMS;
    for (int it = 0; it < 32; ++it) {
        int i = hb*64 + it*2 + ri;
        unsigned p = tmp[i][j];
        unsigned rawd = p & 0xFFFFu, rawi = p >> 16;
        int cfg = (rawi == 0u);            // foreground iff dist-to-1 == 0
        unsigned rsel = cfg ? rawd : rawi; // opposite-class column distance^2
        float bd = (rsel == 0xFFFFu) ? 1e20f : (float)rsel;
        for (int r = 1; r < WW; ++r) {
            float r2 = (float)(r*r);
            if (__all(r2 >= bd)) break;    // exact: candidates only grow past here
            int jl = j - r, jr = j + r;
            unsigned pl = tmp[i][jl & (WW-1)];
            unsigned pr = tmp[i][jr & (WW-1)];
            unsigned sl = cfg ? (pl & 0xFFFFu) : (pl >> 16);
            unsigned sr = cfg ? (pr & 0xFFFFu) : (pr >> 16);
            float gl = (sl == 0xFFFFu) ? 1e20f : (float)sl;
            float gr = (sr == 0xFFFFu) ? 1e20f : (float)sr;
            gl = (jl >= 0) ? gl : 3e38f;
            gr = (jr < WW) ? gr : 3e38f;
            bd = fminf(bd, r2 + fminf(gl, gr));
        }
        float dco = sqrtf(bd);
        cbase[i*WW + j] = dco;
        if (cfg) dmax = fmaxf(dmax, dco);  // dst-component: nonzero only on fg pixels
    }
    for (int off = 32; off > 0; off >>= 1)
        dmax = fmaxf(dmax, __shfl_down(dmax, off));
    if ((t & 63) == 0) wred[t >> 6] = dmax;
    __syncthreads();
    if (t == 0)
        maxdst_blocks[s*2 + hb] = fmaxf(fmaxf(wred[0], wred[1]), fmaxf(wred[2], wred[3]));
}

// ---------------- K2: first/last present slice + thresh (present <=> maxdst>0) --------
__global__ __launch_bounds__(64) void range_kernel(const float* __restrict__ maxdst_blocks,
        int* __restrict__ firstlast, float* __restrict__ thresh)
{
    int b = threadIdx.x;
    if (b < BATCH) {
        int f = 0, l = DEPTH-1;
        for (int d = DEPTH-1; d >= 0; --d) {
            int s = b*DEPTH + d;
            if (fmaxf(maxdst_blocks[2*s], maxdst_blocks[2*s+1]) > 0.0f) f = d;
        }
        for (int d = 0; d < DEPTH; ++d) {
            int s = b*DEPTH + d;
            if (fmaxf(maxdst_blocks[2*s], maxdst_blocks[2*s+1]) > 0.0f) l = d;
        }
        firstlast[b] = f;
        firstlast[BATCH + b] = l;
        int sl = b*DEPTH + l;
        thresh[b] = fmaxf(maxdst_blocks[2*sl], maxdst_blocks[2*sl+1]);
    }
}

// ---------------- K3: vectorized grid-stride reduce of all 5 sums ----------------
__global__ __launch_bounds__(256) void reduce_kernel(const float4* __restrict__ yp4,
        const float4* __restrict__ yt4, const float4* __restrict__ cb4,
        const int* __restrict__ firstlast, const float* __restrict__ thresh,
        float* __restrict__ partials)
{
    float v0=0.f, v1=0.f, v2=0.f, v3=0.f, v4=0.f;
    for (int i4 = blockIdx.x*256 + threadIdx.x; i4 < NV4; i4 += RBLK*256) {
        int idx = i4 << 2;
        int b = idx >> 20;                 // D*H*W = 2^20
        int d = (idx >> 14) & (DEPTH-1);   // H*W = 2^14
        float4 p = yp4[i4];
        float4 q = yt4[i4];
        float4 cc = cb4[i4];
        float th = thresh[b];
        bool inr = (d >= firstlast[b]) && (d <= firstlast[BATCH + b]);
        float c0 = fminf(inr ? cc.x : 0.0f, th);
        float c1 = fminf(inr ? cc.y : 0.0f, th);
        float c2 = fminf(inr ? cc.z : 0.0f, th);
        float c3 = fminf(inr ? cc.w : 0.0f, th);
        float m0 = (q.x > 0.f) ? 1.f : 0.f;
        float m1 = (q.y > 0.f) ? 1.f : 0.f;
        float m2 = (q.z > 0.f) ? 1.f : 0.f;
        float m3 = (q.w > 0.f) ? 1.f : 0.f;
        v0 += p.x*q.x + p.y*q.y + p.z*q.z + p.w*q.w;
        v1 += p.x + p.y + p.z + p.w;
        v2 += q.x + q.y + q.z + q.w;
        v3 += m0*c0 + m1*c1 + m2*c2 + m3*c3;
        v4 += m0 + m1 + m2 + m3;
    }
    for (int off = 32; off > 0; off >>= 1) {
        v0 += __shfl_down(v0, off);
        v1 += __shfl_down(v1, off);
        v2 += __shfl_down(v2, off);
        v3 += __shfl_down(v3, off);
        v4 += __shfl_down(v4, off);
    }
    __shared__ float wsum[4][5];
    int wv = threadIdx.x >> 6;
    if ((threadIdx.x & 63) == 0) {
        wsum[wv][0]=v0; wsum[wv][1]=v1; wsum[wv][2]=v2; wsum[wv][3]=v3; wsum[wv][4]=v4;
    }
    __syncthreads();
    if (threadIdx.x == 0) {
        #pragma unroll
        for (int qd = 0; qd < 5; ++qd)
            partials[qd*RBLK + blockIdx.x] = wsum[0][qd]+wsum[1][qd]+wsum[2][qd]+wsum[3][qd];
    }
}

// ---------------- K4: final scalar ----------------
__global__ __launch_bounds__(1024) void final_kernel(const float* __restrict__ partials,
                                                     float* __restrict__ out)
{
    int t = threadIdx.x;
    double l0 = (double)partials[0*RBLK + t];
    double l1 = (double)partials[1*RBLK + t];
    double l2 = (double)partials[2*RBLK + t];
    double l3 = (double)partials[3*RBLK + t];
    double l4 = (double)partials[4*RBLK + t];
    for (int off = 32; off > 0; off >>= 1) {
        l0 += __shfl_down(l0, off);
        l1 += __shfl_down(l1, off);
        l2 += __shfl_down(l2, off);
        l3 += __shfl_down(l3, off);
        l4 += __shfl_down(l4, off);
    }
    __shared__ double ds[16][5];
    int wv = t >> 6;
    if ((t & 63) == 0) { ds[wv][0]=l0; ds[wv][1]=l1; ds[wv][2]=l2; ds[wv][3]=l3; ds[wv][4]=l4; }
    __syncthreads();
    if (t == 0) {
        double inter=0, spred=0, strue=0, sel=0, cnt=0;
        for (int w = 0; w < 16; ++w) {
            inter += ds[w][0]; spred += ds[w][1]; strue += ds[w][2];
            sel   += ds[w][3]; cnt   += ds[w][4];
        }
        double dice = 2.0 * inter / (spred + strue + 1e-6);
        double mean_sel = sel / cnt;
        double loss = (1.0 - dice) + 3.0 * fabs(1.0 - mean_sel);
        out[0] = (float)loss;
    }
}

extern "C" void kernel_launch(void* const* d_in, const int* in_sizes, int n_in,
                              void* d_out, int out_size, void* d_ws, size_t ws_size,
                              hipStream_t stream) {
    const float* y_pred = (const float*)d_in[0];
    const float* y_true = (const float*)d_in[1];
    float* out = (float*)d_out;
    char* ws = (char*)d_ws;

    float* thresh        = (float*)ws;                 // 2 floats
    int*   firstlast     = (int*)(ws + 64);            // first[2], last[2]
    float* maxdst_blocks = (float*)(ws + 128);         // SLICES*2 floats = 1 KB
    float* partials      = (float*)(ws + 2048);        // 5*1024 floats = 20 KB
    float* combined      = (float*)(ws + 32768);       // 8.4 MB, 16B-aligned

    edt_kernel<<<SLICES*2, 256, 0, stream>>>(y_pred, combined, maxdst_blocks);
    range_kernel<<<1, 64, 0, stream>>>(maxdst_blocks, firstlast, thresh);
    reduce_kernel<<<RBLK, 256, 0, stream>>>((const float4*)y_pred, (const float4*)y_true,
                                            (const float4*)combined, firstlast, thresh, partials);
    final_kernel<<<1, 1024, 0, stream>>>(partials, out);
}